// Round 1
// baseline (594.889 us; speedup 1.0000x reference)
//
#include <hip/hip_runtime.h>
#include <hip/hip_bf16.h>

// out = lambda * ||F^T F_star||_F^2,  F,F* fp32 [16384, 2048]
#define N_ROWS 16384
#define D_DIM  2048

typedef __attribute__((ext_vector_type(8))) short short8;        // 8 bf16 (4 VGPRs)
typedef __attribute__((ext_vector_type(4))) float f32x4;         // MFMA acc
typedef __attribute__((ext_vector_type(8))) unsigned short ushort8;

#define GPTR(p) ((const __attribute__((address_space(1))) void*)(p))
#define LPTR(p) ((__attribute__((address_space(3))) void*)(p))

__device__ __forceinline__ unsigned short f2bf(float x) {
  __hip_bfloat16 b = __float2bfloat16(x);
  return *reinterpret_cast<unsigned short*>(&b);
}

// ---------------- Pass 1: transpose + cast  fp32[N][D] -> bf16[D][N] ----------------
__global__ void __launch_bounds__(256) transpose_cast(
    const float* __restrict__ F, const float* __restrict__ Fs,
    unsigned short* __restrict__ Fb, unsigned short* __restrict__ Fsb) {
  const float* src = blockIdx.z ? Fs : F;
  unsigned short* dst = blockIdx.z ? Fsb : Fb;
  __shared__ float tile[64][65];                 // +1 pad: conflict-free transposed reads
  const int k0 = blockIdx.x * 64;                // 256 k-tiles
  const int m0 = blockIdx.y * 64;                // 32 m-tiles
  const int t = threadIdx.x;

  {   // coalesced float4 loads: 64 rows x 64 cols
    const int lr = t >> 4;
    const int lc = (t & 15) * 4;
#pragma unroll
    for (int p = 0; p < 4; ++p) {
      const int k = lr + p * 16;
      const float4 v = *(const float4*)&src[(size_t)(k0 + k) * D_DIM + m0 + lc];
      tile[k][lc + 0] = v.x; tile[k][lc + 1] = v.y;
      tile[k][lc + 2] = v.z; tile[k][lc + 3] = v.w;
    }
  }
  __syncthreads();
  {   // write bf16 rows of dst (k contiguous), 16B per store
    const int mi = t >> 3;
    const int c = (t & 7) * 8;
#pragma unroll
    for (int p = 0; p < 2; ++p) {
      const int mm = mi + p * 32;
      ushort8 o;
#pragma unroll
      for (int j = 0; j < 8; ++j) o[j] = f2bf(tile[c + j][mm]);
      *(ushort8*)&dst[(size_t)(m0 + mm) * N_ROWS + k0 + c] = o;
    }
  }
}

// ---------------- Pass 2: bf16 MFMA GEMM, 128x128 tile, split-K ----------------
// LDS in fragment order: subtile t (16 m x 32 k) occupies 1024B; lane l holds
// element (m = t*16 + (l&15), k = (l>>4)*8 + j) at t*1024 + l*16 + j*2.
template <int SPLIT>
__global__ void __launch_bounds__(256, 3) gemm_bf16(
    const unsigned short* __restrict__ Fb, const unsigned short* __restrict__ Fsb,
    float* __restrict__ Cpart, const float* __restrict__ lam, float* __restrict__ out) {
  __shared__ unsigned short lds[8192];           // A: [0,4096) shorts, B: [4096,8192)
  const int tid = threadIdx.x;
  const int wave = tid >> 6;
  const int lane = tid & 63;
  const int wm = wave >> 1, wn = wave & 1;       // 2x2 waves, 64x64 each
  const int m_base = blockIdx.y * 128;
  const int n_base = blockIdx.x * 128;
  const int z = blockIdx.z;
  const int KC = N_ROWS / SPLIT;
  const int kbeg = z * KC;
  const int KITER = KC / 32;

  const int row16 = lane & 15;
  const int q8 = (lane >> 4) * 8;
  const int tA0 = 2 * wave, tA1 = 2 * wave + 1;  // each wave stages 2 A + 2 B subtiles
  const unsigned short* gA0 = Fb  + (size_t)(m_base + tA0 * 16 + row16) * N_ROWS + kbeg + q8;
  const unsigned short* gA1 = Fb  + (size_t)(m_base + tA1 * 16 + row16) * N_ROWS + kbeg + q8;
  const unsigned short* gB0 = Fsb + (size_t)(n_base + tA0 * 16 + row16) * N_ROWS + kbeg + q8;
  const unsigned short* gB1 = Fsb + (size_t)(n_base + tA1 * 16 + row16) * N_ROWS + kbeg + q8;
  unsigned short* lA0 = &lds[tA0 * 512];
  unsigned short* lA1 = &lds[tA1 * 512];
  unsigned short* lB0 = &lds[4096 + tA0 * 512];
  unsigned short* lB1 = &lds[4096 + tA1 * 512];

  f32x4 acc[4][4];
#pragma unroll
  for (int i = 0; i < 4; ++i)
#pragma unroll
    for (int j = 0; j < 4; ++j) acc[i][j] = 0.f;

  const unsigned short* lfa = &lds[(wm * 4) * 512];
  const unsigned short* lfb = &lds[4096 + (wn * 4) * 512];

  for (int it = 0; it < KITER; ++it) {
    const int ko = it * 32;
    __builtin_amdgcn_global_load_lds(GPTR(gA0 + ko), LPTR(lA0), 16, 0, 0);
    __builtin_amdgcn_global_load_lds(GPTR(gA1 + ko), LPTR(lA1), 16, 0, 0);
    __builtin_amdgcn_global_load_lds(GPTR(gB0 + ko), LPTR(lB0), 16, 0, 0);
    __builtin_amdgcn_global_load_lds(GPTR(gB1 + ko), LPTR(lB1), 16, 0, 0);
    __syncthreads();                             // compiler drains vmcnt before barrier

    short8 a[4], b[4];
#pragma unroll
    for (int i = 0; i < 4; ++i) a[i] = *(const short8*)&lfa[i * 512 + lane * 8];
#pragma unroll
    for (int j = 0; j < 4; ++j) b[j] = *(const short8*)&lfb[j * 512 + lane * 8];
#pragma unroll
    for (int i = 0; i < 4; ++i)
#pragma unroll
      for (int j = 0; j < 4; ++j)
        acc[i][j] = __builtin_amdgcn_mfma_f32_16x16x32_bf16(a[i], b[j], acc[i][j], 0, 0, 0);
    __syncthreads();
  }

  if (SPLIT > 1) {
    // Frobenius norm is layout-invariant: dump partials flat & coalesced.
    float* cp = Cpart + (size_t)z * (D_DIM * D_DIM)
              + (size_t)(blockIdx.y * 16 + blockIdx.x) * 16384 + wave * 4096;
#pragma unroll
    for (int i = 0; i < 4; ++i)
#pragma unroll
      for (int j = 0; j < 4; ++j)
        *(f32x4*)&cp[(i * 4 + j) * 256 + lane * 4] = acc[i][j];
  } else {
    float s = 0.f;
#pragma unroll
    for (int i = 0; i < 4; ++i)
#pragma unroll
      for (int j = 0; j < 4; ++j)
#pragma unroll
        for (int r = 0; r < 4; ++r) s += acc[i][j][r] * acc[i][j][r];
    for (int off = 32; off > 0; off >>= 1) s += __shfl_down(s, off, 64);
    __shared__ float red[4];
    if (lane == 0) red[wave] = s;
    __syncthreads();
    if (tid == 0) atomicAdd(out, (red[0] + red[1] + red[2] + red[3]) * lam[0]);
  }
}

// ---------------- Pass 3: sum 4 split partials, square, reduce ----------------
__global__ void __launch_bounds__(256) reduce_squares(
    const float* __restrict__ Cpart, const float* __restrict__ lam, float* __restrict__ out) {
  const int NQ = (D_DIM * D_DIM) / 4;            // float4 count per split
  const f32x4* c = (const f32x4*)Cpart;
  float s = 0.f;
  for (int idx = blockIdx.x * 256 + threadIdx.x; idx < NQ; idx += gridDim.x * 256) {
    f32x4 v = c[idx];
    v += c[idx + NQ];
    v += c[idx + 2 * NQ];
    v += c[idx + 3 * NQ];
    s += v.x * v.x + v.y * v.y + v.z * v.z + v.w * v.w;
  }
  for (int off = 32; off > 0; off >>= 1) s += __shfl_down(s, off, 64);
  __shared__ float red[4];
  const int wave = threadIdx.x >> 6, lane = threadIdx.x & 63;
  if (lane == 0) red[wave] = s;
  __syncthreads();
  if (threadIdx.x == 0) atomicAdd(out, (red[0] + red[1] + red[2] + red[3]) * lam[0]);
}

// ---------------- Fallback (only if ws too small): correct, slow ----------------
__global__ void __launch_bounds__(256) fallback_kernel(
    const float* __restrict__ F, const float* __restrict__ Fs,
    const float* __restrict__ lam, float* __restrict__ out) {
  __shared__ float sA[64][16], sB[64][16];
  const int d0 = blockIdx.y * 16, e0 = blockIdx.x * 16;
  const int t = threadIdx.x;
  const int td = t >> 4, te = t & 15;
  float s = 0.f;
  for (int k0 = 0; k0 < N_ROWS; k0 += 64) {
#pragma unroll
    for (int p = 0; p < 4; ++p) {
      const int k = (t >> 4) + p * 16;
      const int cc = t & 15;
      sA[k][cc] = F[(size_t)(k0 + k) * D_DIM + d0 + cc];
      sB[k][cc] = Fs[(size_t)(k0 + k) * D_DIM + e0 + cc];
    }
    __syncthreads();
#pragma unroll
    for (int kk = 0; kk < 64; ++kk) s += sA[kk][td] * sB[kk][te];
    __syncthreads();
  }
  float q = s * s;
  for (int off = 32; off > 0; off >>= 1) q += __shfl_down(q, off, 64);
  __shared__ float red[4];
  if ((t & 63) == 0) red[t >> 6] = q;
  __syncthreads();
  if (t == 0) atomicAdd(out, (red[0] + red[1] + red[2] + red[3]) * lam[0]);
}

extern "C" void kernel_launch(void* const* d_in, const int* in_sizes, int n_in,
                              void* d_out, int out_size, void* d_ws, size_t ws_size,
                              hipStream_t stream) {
  const float* F   = (const float*)d_in[0];
  const float* Fs  = (const float*)d_in[1];
  const float* lam = (const float*)d_in[2];
  float* out = (float*)d_out;
  hipMemsetAsync(d_out, 0, sizeof(float) * (size_t)out_size, stream);

  const size_t bf_bytes = (size_t)D_DIM * N_ROWS * 2;     // 64 MB per matrix
  const size_t need_base = 2 * bf_bytes;                  // 128 MB
  const size_t cpart_bytes = 4ull * D_DIM * D_DIM * 4;    // 64 MB (4 split partials)

  if (ws_size >= need_base + cpart_bytes) {
    unsigned short* Fb  = (unsigned short*)d_ws;
    unsigned short* Fsb = Fb + (size_t)D_DIM * N_ROWS;
    float* Cpart = (float*)((char*)d_ws + need_base);
    transpose_cast<<<dim3(256, 32, 2), 256, 0, stream>>>(F, Fs, Fb, Fsb);
    gemm_bf16<4><<<dim3(16, 16, 4), 256, 0, stream>>>(Fb, Fsb, Cpart, nullptr, nullptr);
    reduce_squares<<<dim3(1024), 256, 0, stream>>>(Cpart, lam, out);
  } else if (ws_size >= need_base) {
    unsigned short* Fb  = (unsigned short*)d_ws;
    unsigned short* Fsb = Fb + (size_t)D_DIM * N_ROWS;
    transpose_cast<<<dim3(256, 32, 2), 256, 0, stream>>>(F, Fs, Fb, Fsb);
    gemm_bf16<1><<<dim3(16, 16, 1), 256, 0, stream>>>(Fb, Fsb, nullptr, lam, out);
  } else {
    fallback_kernel<<<dim3(128, 128), 256, 0, stream>>>(F, Fs, lam, out);
  }
}

// Round 2
// 593.294 us; speedup vs baseline: 1.0027x; 1.0027x over previous
//
#include <hip/hip_runtime.h>
#include <hip/hip_bf16.h>

// out = lambda * ||F^T F_star||_F^2,  F,F* fp32 [16384, 2048]
#define N_ROWS 16384
#define D_DIM  2048
#define SPLITK 8

typedef __attribute__((ext_vector_type(8))) short short8;        // 8 bf16 (4 VGPRs)
typedef __attribute__((ext_vector_type(4))) float f32x4;         // MFMA acc
typedef __attribute__((ext_vector_type(8))) unsigned short ushort8;
typedef __attribute__((ext_vector_type(4))) unsigned short ushort4v;

#define GPTR(p) ((const __attribute__((address_space(1))) void*)(p))
#define LPTR(p) ((__attribute__((address_space(3))) void*)(p))

__device__ __forceinline__ unsigned short f2bf(float x) {
  __hip_bfloat16 b = __float2bfloat16(x);
  return *reinterpret_cast<unsigned short*>(&b);
}
__device__ __forceinline__ float bf2f(unsigned short u) {
  unsigned int v = ((unsigned int)u) << 16;
  return *reinterpret_cast<float*>(&v);
}

// ---------------- Pass 1: transpose + cast  fp32[N][D] -> bf16[D][N] ----------------
// 128(k) x 64(m) tile: 256 B contiguous runs on BOTH the load and store side.
__global__ void __launch_bounds__(256) transpose_cast(
    const float* __restrict__ F, const float* __restrict__ Fs,
    unsigned short* __restrict__ Fb, unsigned short* __restrict__ Fsb) {
  const float* src = blockIdx.z ? Fs : F;
  unsigned short* dst = blockIdx.z ? Fsb : Fb;
  __shared__ float tile[128][65];                // +1 pad
  const int k0 = blockIdx.x * 128;               // 128 k-tiles
  const int m0 = blockIdx.y * 64;                // 32 m-tiles
  const int t = threadIdx.x;

  {   // 128 rows x 64 cols fp32; per instr: 4 rows x 256 B contiguous
    const int lc = (t & 15) * 4;
#pragma unroll
    for (int p = 0; p < 8; ++p) {
      const int k = (t >> 4) + p * 16;
      const float4 v = *(const float4*)&src[(size_t)(k0 + k) * D_DIM + m0 + lc];
      tile[k][lc + 0] = v.x; tile[k][lc + 1] = v.y;
      tile[k][lc + 2] = v.z; tile[k][lc + 3] = v.w;
    }
  }
  __syncthreads();
  {   // 64 dst rows x 128 bf16 (256 B); lanes 0..15 cover one full row
    const int c = (t & 15) * 8;
#pragma unroll
    for (int p = 0; p < 4; ++p) {
      const int mm = (t >> 4) + p * 16;
      ushort8 o;
#pragma unroll
      for (int j = 0; j < 8; ++j) o[j] = f2bf(tile[c + j][mm]);
      *(ushort8*)&dst[(size_t)(m0 + mm) * N_ROWS + k0 + c] = o;
    }
  }
}

// ---------------- Pass 2: bf16 MFMA GEMM, 128x128 tile, split-K=8 ----------------
// LDS in fragment order: subtile t (16 m x 32 k) occupies 1024B; lane l holds
// element (m = t*16 + (l&15), k = (l>>4)*8 + j) at t*1024 + l*16 + j*2.
__global__ void __launch_bounds__(256) gemm_bf16(
    const unsigned short* __restrict__ Fb, const unsigned short* __restrict__ Fsb,
    unsigned short* __restrict__ Cpart) {
  __shared__ unsigned short lds[8192];           // A: [0,4096) shorts, B: [4096,8192)
  const int tid = threadIdx.x;
  const int wave = tid >> 6;
  const int lane = tid & 63;
  const int wm = wave >> 1, wn = wave & 1;       // 2x2 waves, 64x64 each
  const int m_base = blockIdx.y * 128;
  const int n_base = blockIdx.x * 128;
  const int z = blockIdx.z;
  const int KC = N_ROWS / SPLITK;                // 2048
  const int kbeg = z * KC;
  const int KITER = KC / 32;                     // 64

  const int row16 = lane & 15;
  const int q8 = (lane >> 4) * 8;
  const int tA0 = 2 * wave, tA1 = 2 * wave + 1;  // each wave stages 2 A + 2 B subtiles
  const unsigned short* gA0 = Fb  + (size_t)(m_base + tA0 * 16 + row16) * N_ROWS + kbeg + q8;
  const unsigned short* gA1 = Fb  + (size_t)(m_base + tA1 * 16 + row16) * N_ROWS + kbeg + q8;
  const unsigned short* gB0 = Fsb + (size_t)(n_base + tA0 * 16 + row16) * N_ROWS + kbeg + q8;
  const unsigned short* gB1 = Fsb + (size_t)(n_base + tA1 * 16 + row16) * N_ROWS + kbeg + q8;
  unsigned short* lA0 = &lds[tA0 * 512];
  unsigned short* lA1 = &lds[tA1 * 512];
  unsigned short* lB0 = &lds[4096 + tA0 * 512];
  unsigned short* lB1 = &lds[4096 + tA1 * 512];

  f32x4 acc[4][4];
#pragma unroll
  for (int i = 0; i < 4; ++i)
#pragma unroll
    for (int j = 0; j < 4; ++j) acc[i][j] = 0.f;

  const unsigned short* lfa = &lds[(wm * 4) * 512];
  const unsigned short* lfb = &lds[4096 + (wn * 4) * 512];

  for (int it = 0; it < KITER; ++it) {
    const int ko = it * 32;
    __builtin_amdgcn_global_load_lds(GPTR(gA0 + ko), LPTR(lA0), 16, 0, 0);
    __builtin_amdgcn_global_load_lds(GPTR(gA1 + ko), LPTR(lA1), 16, 0, 0);
    __builtin_amdgcn_global_load_lds(GPTR(gB0 + ko), LPTR(lB0), 16, 0, 0);
    __builtin_amdgcn_global_load_lds(GPTR(gB1 + ko), LPTR(lB1), 16, 0, 0);
    __syncthreads();

    short8 a[4], b[4];
#pragma unroll
    for (int i = 0; i < 4; ++i) a[i] = *(const short8*)&lfa[i * 512 + lane * 8];
#pragma unroll
    for (int j = 0; j < 4; ++j) b[j] = *(const short8*)&lfb[j * 512 + lane * 8];
#pragma unroll
    for (int i = 0; i < 4; ++i)
#pragma unroll
      for (int j = 0; j < 4; ++j)
        acc[i][j] = __builtin_amdgcn_mfma_f32_16x16x32_bf16(a[i], b[j], acc[i][j], 0, 0, 0);
    __syncthreads();
  }

  // Frobenius norm is layout-invariant: dump partials flat, coalesced, as bf16.
  unsigned short* cp = Cpart + (size_t)z * (D_DIM * D_DIM)
                     + (size_t)(blockIdx.y * 16 + blockIdx.x) * 16384 + wave * 4096;
#pragma unroll
  for (int i = 0; i < 4; ++i)
#pragma unroll
    for (int j = 0; j < 4; ++j) {
      ushort4v o;
#pragma unroll
      for (int r = 0; r < 4; ++r) o[r] = f2bf(acc[i][j][r]);
      *(ushort4v*)&cp[(i * 4 + j) * 256 + lane * 4] = o;
    }
}

// ---------------- Pass 3: sum 8 bf16 split partials, square, reduce ----------------
__global__ void __launch_bounds__(256) reduce_squares(
    const unsigned short* __restrict__ Cpart, const float* __restrict__ lam,
    float* __restrict__ out) {
  const int NQ = (D_DIM * D_DIM) / 8;            // ushort8 chunks per split
  const ushort8* c = (const ushort8*)Cpart;
  float s = 0.f;
  for (int idx = blockIdx.x * 256 + threadIdx.x; idx < NQ; idx += gridDim.x * 256) {
    float v[8];
#pragma unroll
    for (int j = 0; j < 8; ++j) v[j] = 0.f;
#pragma unroll
    for (int z = 0; z < SPLITK; ++z) {
      ushort8 u = c[(size_t)z * NQ + idx];
#pragma unroll
      for (int j = 0; j < 8; ++j) v[j] += bf2f(u[j]);
    }
#pragma unroll
    for (int j = 0; j < 8; ++j) s += v[j] * v[j];
  }
  for (int off = 32; off > 0; off >>= 1) s += __shfl_down(s, off, 64);
  __shared__ float red[4];
  const int wave = threadIdx.x >> 6, lane = threadIdx.x & 63;
  if (lane == 0) red[wave] = s;
  __syncthreads();
  if (threadIdx.x == 0) atomicAdd(out, (red[0] + red[1] + red[2] + red[3]) * lam[0]);
}

// ---------------- Fallback (only if ws too small): correct, slow ----------------
__global__ void __launch_bounds__(256) fallback_kernel(
    const float* __restrict__ F, const float* __restrict__ Fs,
    const float* __restrict__ lam, float* __restrict__ out) {
  __shared__ float sA[64][16], sB[64][16];
  const int d0 = blockIdx.y * 16, e0 = blockIdx.x * 16;
  const int t = threadIdx.x;
  const int td = t >> 4, te = t & 15;
  float s = 0.f;
  for (int k0 = 0; k0 < N_ROWS; k0 += 64) {
#pragma unroll
    for (int p = 0; p < 4; ++p) {
      const int k = (t >> 4) + p * 16;
      const int cc = t & 15;
      sA[k][cc] = F[(size_t)(k0 + k) * D_DIM + d0 + cc];
      sB[k][cc] = Fs[(size_t)(k0 + k) * D_DIM + e0 + cc];
    }
    __syncthreads();
#pragma unroll
    for (int kk = 0; kk < 64; ++kk) s += sA[kk][td] * sB[kk][te];
    __syncthreads();
  }
  float q = s * s;
  for (int off = 32; off > 0; off >>= 1) q += __shfl_down(q, off, 64);
  __shared__ float red[4];
  if ((t & 63) == 0) red[t >> 6] = q;
  __syncthreads();
  if (t == 0) atomicAdd(out, (red[0] + red[1] + red[2] + red[3]) * lam[0]);
}

extern "C" void kernel_launch(void* const* d_in, const int* in_sizes, int n_in,
                              void* d_out, int out_size, void* d_ws, size_t ws_size,
                              hipStream_t stream) {
  const float* F   = (const float*)d_in[0];
  const float* Fs  = (const float*)d_in[1];
  const float* lam = (const float*)d_in[2];
  float* out = (float*)d_out;
  hipMemsetAsync(d_out, 0, sizeof(float) * (size_t)out_size, stream);

  const size_t bf_bytes = (size_t)D_DIM * N_ROWS * 2;             // 64 MB per matrix
  const size_t cpart_bytes = (size_t)SPLITK * D_DIM * D_DIM * 2;  // 64 MB (bf16 partials)
  const size_t need = 2 * bf_bytes + cpart_bytes;                 // 192 MB

  if (ws_size >= need) {
    unsigned short* Fb  = (unsigned short*)d_ws;
    unsigned short* Fsb = Fb + (size_t)D_DIM * N_ROWS;
    unsigned short* Cpart = (unsigned short*)((char*)d_ws + 2 * bf_bytes);
    transpose_cast<<<dim3(128, 32, 2), 256, 0, stream>>>(F, Fs, Fb, Fsb);
    gemm_bf16<<<dim3(16, 16, SPLITK), 256, 0, stream>>>(Fb, Fsb, Cpart);
    reduce_squares<<<dim3(1024), 256, 0, stream>>>(Cpart, lam, out);
  } else {
    fallback_kernel<<<dim3(128, 128), 256, 0, stream>>>(F, Fs, lam, out);
  }
}